// Round 1
// baseline (1497.394 us; speedup 1.0000x reference)
//
#include <hip/hip_runtime.h>

// Affine_Linear_Abla_Quat: fused quat->rotation->terms->3xGEMM
// Shapes: X (8,4096,256,3) f32, J (8,4096,256,4) f32, A/B/C (256,256) f32
// Out Y (8,4096,256,3) f32.
//
// Structure: one block of 256 threads handles G=4 (b,n) pairs.
// Phase 1: per-element quat math -> 9 term floats into LDS (padded to 12).
// Phase 2: thread owns output row f=tid; loops e, keeps A/B/C[f][e] in regs
//          (reused across all G pairs), terms via broadcast ds_read_b128.

constexpr int Dd  = 256;   // D (= F)
constexpr int Gp  = 4;     // (b,n) pairs per block
constexpr int TPB = 256;

__global__ __launch_bounds__(TPB, 2)
void alaq_fused_kernel(const float* __restrict__ X,
                       const float* __restrict__ J,
                       const float* __restrict__ A,
                       const float* __restrict__ B,
                       const float* __restrict__ Cm,
                       float* __restrict__ Y)
{
    // 9 floats used, padded to 12 so float4 loads are 16B-aligned (48B stride)
    __shared__ float T[Gp][Dd][12];

    const int tid = threadIdx.x;
    const long bn0 = (long)blockIdx.x * Gp;

    // ---------------- Phase 1: terms ----------------
    #pragma unroll
    for (int g = 0; g < Gp; ++g) {
        const long base = (bn0 + g) * Dd + tid;
        const float4 q = *reinterpret_cast<const float4*>(J + base * 4); // 16B aligned
        const float* xp = X + base * 3;
        const float x0 = xp[0], x1 = xp[1], x2 = xp[2];

        const float nsq = q.x*q.x + q.y*q.y + q.z*q.z + q.w*q.w;
        const float inv = 1.0f / fmaxf(sqrtf(nsq), 1e-12f);
        const float qx = q.x*inv, qy = q.y*inv, qz = q.z*inv, qw = q.w*inv;
        const float s = 2.0f / (qw*qw + qx*qx + qy*qy + qz*qz);

        const float r00 = 1.0f - s*(qy*qy + qz*qz);
        const float r01 = s*(qx*qy - qz*qw);
        const float r02 = s*(qx*qz + qy*qw);
        const float r10 = s*(qx*qy + qz*qw);
        const float r11 = 1.0f - s*(qx*qx + qz*qz);
        const float r12 = s*(qy*qz - qx*qw);
        const float r20 = s*(qx*qz - qy*qw);
        const float r21 = s*(qy*qz + qx*qw);
        const float r22 = 1.0f - s*(qx*qx + qy*qy);

        // RTX = R^T x  (rt_i = sum_k R[k][i] * x[k])
        const float rt0 = r00*x0 + r10*x1 + r20*x2;
        const float rt1 = r01*x0 + r11*x1 + r21*x2;
        const float rt2 = r02*x0 + r12*x1 + r22*x2;

        // a[i] = R[i][0]*rt0 + R[i][1]*rt1
        // b[i] = R[i][1]*rt0 - R[i][0]*rt1
        // c[i] = R[i][2]*rt2
        float4 t0, t1;
        t0.x = r00*rt0 + r01*rt1;   // a0
        t0.y = r10*rt0 + r11*rt1;   // a1
        t0.z = r20*rt0 + r21*rt1;   // a2
        t0.w = r01*rt0 - r00*rt1;   // b0
        t1.x = r11*rt0 - r10*rt1;   // b1
        t1.y = r21*rt0 - r20*rt1;   // b2
        t1.z = r02*rt2;             // c0
        t1.w = r12*rt2;             // c1
        const float t8 = r22*rt2;   // c2

        float* t = T[g][tid];
        *reinterpret_cast<float4*>(&t[0]) = t0;
        *reinterpret_cast<float4*>(&t[4]) = t1;
        t[8] = t8;
    }
    __syncthreads();

    // ---------------- Phase 2: GEMM rows ----------------
    float acc[Gp][3];
    #pragma unroll
    for (int g = 0; g < Gp; ++g) {
        acc[g][0] = 0.0f; acc[g][1] = 0.0f; acc[g][2] = 0.0f;
    }

    const float* Ar = A  + (long)tid * Dd;
    const float* Br = B  + (long)tid * Dd;
    const float* Cr = Cm + (long)tid * Dd;

    for (int e0 = 0; e0 < Dd; e0 += 4) {
        const float4 a4 = *reinterpret_cast<const float4*>(Ar + e0);
        const float4 b4 = *reinterpret_cast<const float4*>(Br + e0);
        const float4 c4 = *reinterpret_cast<const float4*>(Cr + e0);
        const float av[4] = {a4.x, a4.y, a4.z, a4.w};
        const float bv[4] = {b4.x, b4.y, b4.z, b4.w};
        const float cv[4] = {c4.x, c4.y, c4.z, c4.w};

        #pragma unroll
        for (int ee = 0; ee < 4; ++ee) {
            const float af = av[ee], bf = bv[ee], cf = cv[ee];
            #pragma unroll
            for (int g = 0; g < Gp; ++g) {
                const float* t = T[g][e0 + ee];
                const float4 t0 = *reinterpret_cast<const float4*>(&t[0]); // a0 a1 a2 b0
                const float4 t1 = *reinterpret_cast<const float4*>(&t[4]); // b1 b2 c0 c1
                const float  t8 = t[8];                                    // c2
                acc[g][0] += af*t0.x + bf*t0.w + cf*t1.z;
                acc[g][1] += af*t0.y + bf*t1.x + cf*t1.w;
                acc[g][2] += af*t0.z + bf*t1.y + cf*t8;
            }
        }
    }

    #pragma unroll
    for (int g = 0; g < Gp; ++g) {
        const long obase = ((bn0 + g) * Dd + tid) * 3;
        Y[obase + 0] = acc[g][0];
        Y[obase + 1] = acc[g][1];
        Y[obase + 2] = acc[g][2];
    }
}

extern "C" void kernel_launch(void* const* d_in, const int* in_sizes, int n_in,
                              void* d_out, int out_size, void* d_ws, size_t ws_size,
                              hipStream_t stream) {
    const float* X  = (const float*)d_in[0];
    const float* J  = (const float*)d_in[1];
    const float* A  = (const float*)d_in[2];
    const float* B  = (const float*)d_in[3];
    const float* Cm = (const float*)d_in[4];
    float* Y = (float*)d_out;

    // number of (b,n) pairs from J's flat size: (Bb*N*D*4) / (D*4)
    const int nbn = in_sizes[1] / (Dd * 4);
    const int blocks = nbn / Gp;   // 32768/4 = 8192

    alaq_fused_kernel<<<blocks, TPB, 0, stream>>>(X, J, A, B, Cm, Y);
}

// Round 3
// 161.356 us; speedup vs baseline: 9.2801x; 9.2801x over previous
//
#include <hip/hip_runtime.h>

// Affine_Linear_Abla_Quat — bf16 MFMA formulation.
// Per block: G=16 (b,n) pairs.
//   Phase 1: quat math per element -> 9 terms, bf16, into LDS TT[48][768+pad]
//            TT[p*3+i][term*256+e]  (term 0/1/2 -> A/B/C)
//   Phase 2: D[m=p*3+i][f] = sum_k TT[m][k] * W[f][k],
//            W = bf16 copies of A,B,C rows (built by prologue into d_ws,
//            L2-resident, loaded straight into B-fragments from global).
// mfma_f32_16x16x32_bf16: A-frag lane l = A[m0+(l&15)][k0+8*(l>>4)+j] (k-contig),
// B-frag lane l = B[k0+8*(l>>4)+j][n0+(l&15)] (k-contig given W row-major [f][k]),
// D: col=lane&15 (n), row=(lane>>4)*4+reg (m).

typedef __bf16 bf16_t;
typedef __attribute__((ext_vector_type(8))) __bf16 bf16x8;
typedef __attribute__((ext_vector_type(4))) __bf16 bf16x4;
typedef __attribute__((ext_vector_type(4))) float f32x4;

constexpr int Dd    = 256;  // D == F
constexpr int Gp    = 16;   // pairs per block -> M = 48
constexpr int TPB   = 512;  // 8 waves
constexpr int PITCH = 776;  // 768 + 8 bf16 pad: rows 16B-aligned, bank-staggered

__device__ __forceinline__ bf16_t to_bf16(float f) {
    unsigned u = __builtin_bit_cast(unsigned, f);
    u += 0x7FFFu + ((u >> 16) & 1u);          // round-to-nearest-even
    unsigned short h = (unsigned short)(u >> 16);
    return __builtin_bit_cast(bf16_t, h);
}

// ---- prologue: A,B,C (f32 256x256 each) -> W bf16 [3][256][256] in d_ws ----
__global__ __launch_bounds__(256)
void convert_w_kernel(const float* __restrict__ A, const float* __restrict__ B,
                      const float* __restrict__ C, bf16_t* __restrict__ W)
{
    const int e4 = (blockIdx.x * 256 + threadIdx.x) * 4;   // 0..196604
    const float* src;
    if (e4 < 65536)        src = A + e4;
    else if (e4 < 131072)  src = B + (e4 - 65536);
    else                   src = C + (e4 - 131072);
    const float4 v = *reinterpret_cast<const float4*>(src);
    bf16x4 o;
    o[0] = to_bf16(v.x); o[1] = to_bf16(v.y); o[2] = to_bf16(v.z); o[3] = to_bf16(v.w);
    *reinterpret_cast<bf16x4*>(W + e4) = o;
}

// ------------------------------ main kernel ------------------------------
__global__ __launch_bounds__(TPB)
void alaq_mfma_kernel(const float* __restrict__ X, const float* __restrict__ J,
                      const bf16_t* __restrict__ W, float* __restrict__ Y)
{
    __shared__ bf16_t TT[48 * PITCH];   // 74.5 KB

    const int tid = threadIdx.x;
    const long bn0 = (long)blockIdx.x * Gp;

    // ---------------- Phase 1: terms -> LDS ----------------
    #pragma unroll
    for (int rr = 0; rr < 8; ++rr) {
        const int idx = rr * TPB + tid;        // 0..4095
        const int p = idx >> 8;                // pair in block
        const int e = idx & 255;
        const long base = (bn0 + p) * Dd + e;

        const float4 q = *reinterpret_cast<const float4*>(J + base * 4);
        const float* xp = X + base * 3;
        const float x0 = xp[0], x1 = xp[1], x2 = xp[2];

        const float nsq = q.x*q.x + q.y*q.y + q.z*q.z + q.w*q.w;
        const float inv = 1.0f / fmaxf(sqrtf(nsq), 1e-12f);
        const float qx = q.x*inv, qy = q.y*inv, qz = q.z*inv, qw = q.w*inv;
        const float s = 2.0f / (qw*qw + qx*qx + qy*qy + qz*qz);

        const float r00 = 1.0f - s*(qy*qy + qz*qz);
        const float r01 = s*(qx*qy - qz*qw);
        const float r02 = s*(qx*qz + qy*qw);
        const float r10 = s*(qx*qy + qz*qw);
        const float r11 = 1.0f - s*(qx*qx + qz*qz);
        const float r12 = s*(qy*qz - qx*qw);
        const float r20 = s*(qx*qz - qy*qw);
        const float r21 = s*(qy*qz + qx*qw);
        const float r22 = 1.0f - s*(qx*qx + qy*qy);

        const float rt0 = r00*x0 + r10*x1 + r20*x2;
        const float rt1 = r01*x0 + r11*x1 + r21*x2;
        const float rt2 = r02*x0 + r12*x1 + r22*x2;

        const int row = (p * 3) * PITCH;
        // a_i -> k = e ; b_i -> k = 256+e ; c_i -> k = 512+e
        TT[row             + e      ] = to_bf16(r00*rt0 + r01*rt1);
        TT[row +     PITCH + e      ] = to_bf16(r10*rt0 + r11*rt1);
        TT[row + 2 * PITCH + e      ] = to_bf16(r20*rt0 + r21*rt1);
        TT[row             + 256 + e] = to_bf16(r01*rt0 - r00*rt1);
        TT[row +     PITCH + 256 + e] = to_bf16(r11*rt0 - r10*rt1);
        TT[row + 2 * PITCH + 256 + e] = to_bf16(r21*rt0 - r20*rt1);
        TT[row             + 512 + e] = to_bf16(r02*rt2);
        TT[row +     PITCH + 512 + e] = to_bf16(r12*rt2);
        TT[row + 2 * PITCH + 512 + e] = to_bf16(r22*rt2);
    }
    __syncthreads();

    // ---------------- Phase 2: MFMA GEMM ----------------
    const int w  = tid >> 6;          // wave 0..7, owns n-tiles {2w, 2w+1}
    const int l  = tid & 63;
    const int lr = l & 15;            // row/col within fragment
    const int lq = l >> 4;            // k-group

    f32x4 acc[3][2] = {};

    const int f0 = (2 * w    ) * 16 + lr;
    const int f1 = (2 * w + 1) * 16 + lr;

    #pragma unroll 4
    for (int k0 = 0; k0 < 24; ++k0) {
        const int term = k0 >> 3;                       // which of A/B/C
        const int eb   = ((k0 & 7) << 5) + (lq << 3);   // e-offset within term
        const bf16x8 b0 = *reinterpret_cast<const bf16x8*>(W + (term << 16) + f0 * 256 + eb);
        const bf16x8 b1 = *reinterpret_cast<const bf16x8*>(W + (term << 16) + f1 * 256 + eb);

        const int kcol = (k0 << 5) + (lq << 3);
        const bf16x8 a0 = *reinterpret_cast<const bf16x8*>(&TT[( 0 + lr) * PITCH + kcol]);
        const bf16x8 a1 = *reinterpret_cast<const bf16x8*>(&TT[(16 + lr) * PITCH + kcol]);
        const bf16x8 a2 = *reinterpret_cast<const bf16x8*>(&TT[(32 + lr) * PITCH + kcol]);

        acc[0][0] = __builtin_amdgcn_mfma_f32_16x16x32_bf16(a0, b0, acc[0][0], 0, 0, 0);
        acc[1][0] = __builtin_amdgcn_mfma_f32_16x16x32_bf16(a1, b0, acc[1][0], 0, 0, 0);
        acc[2][0] = __builtin_amdgcn_mfma_f32_16x16x32_bf16(a2, b0, acc[2][0], 0, 0, 0);
        acc[0][1] = __builtin_amdgcn_mfma_f32_16x16x32_bf16(a0, b1, acc[0][1], 0, 0, 0);
        acc[1][1] = __builtin_amdgcn_mfma_f32_16x16x32_bf16(a1, b1, acc[1][1], 0, 0, 0);
        acc[2][1] = __builtin_amdgcn_mfma_f32_16x16x32_bf16(a2, b1, acc[2][1], 0, 0, 0);
    }

    // ---------------- Epilogue: D[m][f] -> Y[(bn0+p)*768 + f*3 + i] ----------------
    #pragma unroll
    for (int mi = 0; mi < 3; ++mi) {
        #pragma unroll
        for (int ni = 0; ni < 2; ++ni) {
            const int f = (2 * w + ni) * 16 + lr;
            #pragma unroll
            for (int r = 0; r < 4; ++r) {
                const int m = mi * 16 + lq * 4 + r;   // 0..47
                const int p = m / 3;
                const int i = m - p * 3;
                Y[(bn0 + p) * 768 + f * 3 + i] = acc[mi][ni][r];
            }
        }
    }
}

extern "C" void kernel_launch(void* const* d_in, const int* in_sizes, int n_in,
                              void* d_out, int out_size, void* d_ws, size_t ws_size,
                              hipStream_t stream) {
    const float* X  = (const float*)d_in[0];
    const float* J  = (const float*)d_in[1];
    const float* A  = (const float*)d_in[2];
    const float* B  = (const float*)d_in[3];
    const float* Cm = (const float*)d_in[4];
    float* Y = (float*)d_out;
    bf16_t* W = (bf16_t*)d_ws;    // 3 * 256 * 256 * 2B = 393,216 B

    convert_w_kernel<<<192, 256, 0, stream>>>(A, B, Cm, W);

    const int nbn = in_sizes[1] / (Dd * 4);       // 32768
    const int blocks = nbn / Gp;                  // 2048
    alaq_mfma_kernel<<<blocks, TPB, 0, stream>>>(X, J, W, Y);
}

// Round 4
// 144.530 us; speedup vs baseline: 10.3604x; 1.1164x over previous
//
#include <hip/hip_runtime.h>

// Affine_Linear_Abla_Quat — bf16 MFMA, v3.
// v2 -> v3: (1) PITCH 776->768 + XOR-swizzle of 16B granules by (row&7):
//           conflict-free ds_read_b128 frag reads and ds_write_b16 term writes.
//           (2) phase-1 loads batched into registers (one latency exposure).
//           (3) k-loop fully unrolled; __launch_bounds__(512,4) caps VGPR at 128
//           so 2 blocks/CU (16 waves) stay resident.

typedef __bf16 bf16_t;
typedef __attribute__((ext_vector_type(8))) __bf16 bf16x8;
typedef __attribute__((ext_vector_type(4))) __bf16 bf16x4;
typedef __attribute__((ext_vector_type(4))) float f32x4;

constexpr int Dd  = 256;   // D == F
constexpr int Gp  = 16;    // pairs per block -> M = 48
constexpr int TPB = 512;   // 8 waves

__device__ __forceinline__ bf16_t to_bf16(float f) {
    unsigned u = __builtin_bit_cast(unsigned, f);
    u += 0x7FFFu + ((u >> 16) & 1u);          // round-to-nearest-even
    unsigned short h = (unsigned short)(u >> 16);
    return __builtin_bit_cast(bf16_t, h);
}

// swizzled element index into TT: row-major [48][768], 16B granule XOR (row&7)
__device__ __forceinline__ int swz(int row, int k) {
    return row * 768 + (k ^ ((row & 7) << 3));
}

// ---- prologue: A,B,C (f32 256x256 each) -> W bf16 [3][256][256] in d_ws ----
__global__ __launch_bounds__(256)
void convert_w_kernel(const float* __restrict__ A, const float* __restrict__ B,
                      const float* __restrict__ C, bf16_t* __restrict__ W)
{
    const int e4 = (blockIdx.x * 256 + threadIdx.x) * 4;
    const float* src;
    if (e4 < 65536)        src = A + e4;
    else if (e4 < 131072)  src = B + (e4 - 65536);
    else                   src = C + (e4 - 131072);
    const float4 v = *reinterpret_cast<const float4*>(src);
    bf16x4 o;
    o[0] = to_bf16(v.x); o[1] = to_bf16(v.y); o[2] = to_bf16(v.z); o[3] = to_bf16(v.w);
    *reinterpret_cast<bf16x4*>(W + e4) = o;
}

// ------------------------------ main kernel ------------------------------
__global__ __launch_bounds__(TPB, 4)
void alaq_mfma_kernel(const float* __restrict__ X, const float* __restrict__ J,
                      const bf16_t* __restrict__ W, float* __restrict__ Y)
{
    __shared__ bf16_t TT[48 * 768];   // 73,728 B -> 2 blocks/CU

    const int tid = threadIdx.x;
    const long bn0 = (long)blockIdx.x * Gp;
    const long ebase = bn0 * Dd;      // element index of this block's first elem

    // ---------------- Phase 1: batched loads, then compute ----------------
    float4 qv[8];
    float  xv[8][3];
    #pragma unroll
    for (int rr = 0; rr < 8; ++rr) {
        const long base = ebase + rr * TPB + tid;
        qv[rr] = *reinterpret_cast<const float4*>(J + base * 4);
        const float* xp = X + base * 3;
        xv[rr][0] = xp[0]; xv[rr][1] = xp[1]; xv[rr][2] = xp[2];
    }

    #pragma unroll
    for (int rr = 0; rr < 8; ++rr) {
        const int idx = rr * TPB + tid;        // 0..4095
        const int p = idx >> 8;
        const int e = idx & 255;

        const float4 q = qv[rr];
        const float x0 = xv[rr][0], x1 = xv[rr][1], x2 = xv[rr][2];

        const float nsq = q.x*q.x + q.y*q.y + q.z*q.z + q.w*q.w;
        const float inv = 1.0f / fmaxf(sqrtf(nsq), 1e-12f);
        const float qx = q.x*inv, qy = q.y*inv, qz = q.z*inv, qw = q.w*inv;
        const float s = 2.0f / (qw*qw + qx*qx + qy*qy + qz*qz);

        const float r00 = 1.0f - s*(qy*qy + qz*qz);
        const float r01 = s*(qx*qy - qz*qw);
        const float r02 = s*(qx*qz + qy*qw);
        const float r10 = s*(qx*qy + qz*qw);
        const float r11 = 1.0f - s*(qx*qx + qz*qz);
        const float r12 = s*(qy*qz - qx*qw);
        const float r20 = s*(qx*qz - qy*qw);
        const float r21 = s*(qy*qz + qx*qw);
        const float r22 = 1.0f - s*(qx*qx + qy*qy);

        const float rt0 = r00*x0 + r10*x1 + r20*x2;
        const float rt1 = r01*x0 + r11*x1 + r21*x2;
        const float rt2 = r02*x0 + r12*x1 + r22*x2;

        const int row = p * 3;
        TT[swz(row    ,       e)] = to_bf16(r00*rt0 + r01*rt1);
        TT[swz(row + 1,       e)] = to_bf16(r10*rt0 + r11*rt1);
        TT[swz(row + 2,       e)] = to_bf16(r20*rt0 + r21*rt1);
        TT[swz(row    , 256 + e)] = to_bf16(r01*rt0 - r00*rt1);
        TT[swz(row + 1, 256 + e)] = to_bf16(r11*rt0 - r10*rt1);
        TT[swz(row + 2, 256 + e)] = to_bf16(r21*rt0 - r20*rt1);
        TT[swz(row    , 512 + e)] = to_bf16(r02*rt2);
        TT[swz(row + 1, 512 + e)] = to_bf16(r12*rt2);
        TT[swz(row + 2, 512 + e)] = to_bf16(r22*rt2);
    }
    __syncthreads();

    // ---------------- Phase 2: MFMA GEMM ----------------
    const int w  = tid >> 6;          // wave 0..7, owns f-strips {2w, 2w+1}
    const int l  = tid & 63;
    const int lr = l & 15;
    const int lq = l >> 4;

    f32x4 acc[3][2] = {};

    const int f0 = (2 * w) * 16 + lr;
    const bf16_t* Wf0 = W + f0 * 256 + (lq << 3);
    const bf16_t* Wf1 = Wf0 + 16 * 256;
    const int swzmask = (lr & 7) << 3;

    #pragma unroll
    for (int k0 = 0; k0 < 24; ++k0) {
        const int term = k0 >> 3;
        const int eb   = (k0 & 7) << 5;
        const bf16x8 b0 = *reinterpret_cast<const bf16x8*>(Wf0 + (term << 16) + eb);
        const bf16x8 b1 = *reinterpret_cast<const bf16x8*>(Wf1 + (term << 16) + eb);

        const int kswz = (((k0 << 5) + (lq << 3)) ^ swzmask);
        const bf16x8 a0 = *reinterpret_cast<const bf16x8*>(&TT[         lr  * 768 + kswz]);
        const bf16x8 a1 = *reinterpret_cast<const bf16x8*>(&TT[(16 +    lr) * 768 + kswz]);
        const bf16x8 a2 = *reinterpret_cast<const bf16x8*>(&TT[(32 +    lr) * 768 + kswz]);

        acc[0][0] = __builtin_amdgcn_mfma_f32_16x16x32_bf16(a0, b0, acc[0][0], 0, 0, 0);
        acc[1][0] = __builtin_amdgcn_mfma_f32_16x16x32_bf16(a1, b0, acc[1][0], 0, 0, 0);
        acc[2][0] = __builtin_amdgcn_mfma_f32_16x16x32_bf16(a2, b0, acc[2][0], 0, 0, 0);
        acc[0][1] = __builtin_amdgcn_mfma_f32_16x16x32_bf16(a0, b1, acc[0][1], 0, 0, 0);
        acc[1][1] = __builtin_amdgcn_mfma_f32_16x16x32_bf16(a1, b1, acc[1][1], 0, 0, 0);
        acc[2][1] = __builtin_amdgcn_mfma_f32_16x16x32_bf16(a2, b1, acc[2][1], 0, 0, 0);
    }

    // ---------------- Epilogue ----------------
    #pragma unroll
    for (int mi = 0; mi < 3; ++mi) {
        #pragma unroll
        for (int ni = 0; ni < 2; ++ni) {
            const int f = (2 * w + ni) * 16 + lr;
            #pragma unroll
            for (int r = 0; r < 4; ++r) {
                const int m = mi * 16 + lq * 4 + r;   // 0..47
                const int p = m / 3;
                const int i = m - p * 3;
                Y[(bn0 + p) * 768 + f * 3 + i] = acc[mi][ni][r];
            }
        }
    }
}

extern "C" void kernel_launch(void* const* d_in, const int* in_sizes, int n_in,
                              void* d_out, int out_size, void* d_ws, size_t ws_size,
                              hipStream_t stream) {
    const float* X  = (const float*)d_in[0];
    const float* J  = (const float*)d_in[1];
    const float* A  = (const float*)d_in[2];
    const float* B  = (const float*)d_in[3];
    const float* Cm = (const float*)d_in[4];
    float* Y = (float*)d_out;
    bf16_t* W = (bf16_t*)d_ws;    // 393,216 B

    convert_w_kernel<<<192, 256, 0, stream>>>(A, B, Cm, W);

    const int nbn = in_sizes[1] / (Dd * 4);       // 32768
    const int blocks = nbn / Gp;                  // 2048
    alaq_mfma_kernel<<<blocks, TPB, 0, stream>>>(X, J, W, Y);
}